// Round 10
// baseline (135.295 us; speedup 1.0000x reference)
//
#include <hip/hip_runtime.h>
#include <hip/hip_bf16.h>
#include <stdint.h>

#define Bn 2
#define Nn 256
#define Dn 128

typedef __attribute__((ext_vector_type(8))) short short8;
typedef __attribute__((ext_vector_type(4))) float f32x4;

__device__ __forceinline__ float sigm(float x){
    return __builtin_amdgcn_rcpf(1.0f + __builtin_amdgcn_exp2f(-1.44269504f*x));
}
__device__ __forceinline__ unsigned short f2b(float f){
    __hip_bfloat16 h = __float2bfloat16(f);   // RNE; compiler can pack cvt_pk
    return __builtin_bit_cast(unsigned short, h);
}
__device__ __forceinline__ float b2f(unsigned short h){
    return __uint_as_float(((unsigned)h)<<16);
}

// ---------------------------------------------------------------------------
// K0: W[k][n] fp32 -> WTf in MFMA B-fragment order:
//   frag f = (mat*8 + nt)*4 + kc ; lane l, elem e holds
//   W[k = kc*32 + (l>>4)*8 + e][n = nt*16 + (l&15)]
// mats: 0=Wl 1=Wr 2=Wlg 3=Wrg 4=Wog 5=Wo
// ---------------------------------------------------------------------------
__global__ __launch_bounds__(256) void k0_wt(
    const float* __restrict__ Wl, const float* __restrict__ Wr,
    const float* __restrict__ Wlg, const float* __restrict__ Wrg,
    const float* __restrict__ Wog, const float* __restrict__ Wo,
    unsigned short* __restrict__ WTf)
{
    int mat = blockIdx.x >> 3, nt = blockIdx.x & 7;
    const float* W = (mat==0)?Wl:(mat==1)?Wr:(mat==2)?Wlg:(mat==3)?Wrg:(mat==4)?Wog:Wo;
    int t = threadIdx.x;
    int kc = t >> 6, l = t & 63;
    int n  = nt*16 + (l & 15);
    int k0 = kc*32 + (l >> 4)*8;
    short8 sv;
    #pragma unroll
    for (int e=0;e<8;++e) sv[e] = (short)f2b(W[(k0+e)*128 + n]);
    *(short8*)&WTf[(((mat*8 + nt)*4 + kc) << 9) + l*8] = sv;
}

// ---------------------------------------------------------------------------
// K1: LN1 + 5 projections via MFMA.  Block = 64 rows (b, p0..p0+64, q fixed),
// 512 threads / 8 waves.  Wave w owns all 64 rows x 16 cols (n = w*16..):
// aF[4][4] row-frags (64 VGPR), per-pass acc 32 AGPR -> each B-frag load
// feeds 4 MFMAs (weight L2 stream halved vs 32-row blocks).
// Passes {Wl,Wlg} -> {Wr,Wrg} -> {Wog}.  launch_bounds(512,4): 128-reg
// budget, no spill (r7 lesson).  LDS 54.5KB -> 2 blocks/CU.
// og stored bf16 in d_out at 512B/row stride (in-place-safe for k3).
// R9 BUG FIX: og writeout covered only segs 0..7 (64 of 128 n-els/row) ->
// half the gate was zero -> absmax 0.658. Now each thread writes 2 short8.
// ---------------------------------------------------------------------------
__global__ __launch_bounds__(512, 4) void k1_proj(
    const float* __restrict__ x, const int* __restrict__ msk,
    const float* __restrict__ g1, const float* __restrict__ b1,
    const unsigned short* __restrict__ WTf,
    const float* __restrict__ bl, const float* __restrict__ br,
    const float* __restrict__ blg, const float* __restrict__ brg,
    const float* __restrict__ bog,
    unsigned short* __restrict__ leftT, unsigned short* __restrict__ rightT,
    unsigned short* __restrict__ og)
{
    __shared__ __align__(16) unsigned short xn_s[64][136];   // reused as og_s later
    __shared__ __align__(16) unsigned short lds_l[128][72];
    __shared__ __align__(16) unsigned short lds_r[128][72];
    __shared__ float mask_s[64];

    const int tid = threadIdx.x;
    const int wv = tid>>6, lane = tid&63;
    int bid = blockIdx.x;
    int pb  = bid & 3;
    int q   = (bid >> 2) & 255;
    int b   = bid >> 10;
    int p0  = pb * 64;

    // Phase A: LN of 64 rows, 8 waves x 8 rows; all x-loads issued up front
    {
        float a0[8], a1[8];
        #pragma unroll
        for (int rr=0; rr<8; ++rr){
            int r = wv*8 + rr;
            long row = ((long)(b*Nn + p0 + r))*Nn + q;
            const float* xr = x + row*Dn;
            a0[rr] = xr[lane]; a1[rr] = xr[lane+64];
        }
        if (lane < 8){
            int r = wv*8 + lane;
            mask_s[r] = (float)(msk[b*Nn + p0 + r] * msk[b*Nn + q]);
        }
        #pragma unroll
        for (int rr=0; rr<8; ++rr){
            int r = wv*8 + rr;
            float s = a0[rr]+a1[rr], sq = a0[rr]*a0[rr] + a1[rr]*a1[rr];
            #pragma unroll
            for (int m=1; m<64; m<<=1){ s += __shfl_xor(s,m); sq += __shfl_xor(sq,m); }
            float mean = s*(1.f/128.f);
            float var  = sq*(1.f/128.f) - mean*mean;
            float rstd = rsqrtf(var + 1e-5f);
            xn_s[r][lane]    = f2b((a0[rr]-mean)*rstd*g1[lane]    + b1[lane]);
            xn_s[r][lane+64] = f2b((a1[rr]-mean)*rstd*g1[lane+64] + b1[lane+64]);
        }
    }
    __syncthreads();

    const int l15 = lane & 15, g = lane >> 4;
    const int n = wv*16 + l15;

    // A-frags: 4 row-tiles x 4 k-chunks (held across passes)
    short8 aF[4][4];
    #pragma unroll
    for (int rt=0; rt<4; ++rt)
        #pragma unroll
        for (int kc=0; kc<4; ++kc)
            aF[rt][kc] = *(const short8*)&xn_s[rt*16 + l15][kc*32 + g*8];
    __syncthreads();   // all aF reads done -> xn_s reusable as og_s

    // Pass L: mats 0 (Wl), 2 (Wlg)
    {
        f32x4 aV[4] = {{0,0,0,0},{0,0,0,0},{0,0,0,0},{0,0,0,0}};
        f32x4 aG[4] = {{0,0,0,0},{0,0,0,0},{0,0,0,0},{0,0,0,0}};
        #pragma unroll
        for (int kc=0; kc<4; ++kc){
            short8 bF = *(const short8*)&WTf[(((0*8 + wv)*4 + kc) << 9) + lane*8];
            #pragma unroll
            for (int rt=0; rt<4; ++rt)
                aV[rt] = __builtin_amdgcn_mfma_f32_16x16x32_bf16(aF[rt][kc], bF, aV[rt], 0,0,0);
        }
        #pragma unroll
        for (int kc=0; kc<4; ++kc){
            short8 bF = *(const short8*)&WTf[(((2*8 + wv)*4 + kc) << 9) + lane*8];
            #pragma unroll
            for (int rt=0; rt<4; ++rt)
                aG[rt] = __builtin_amdgcn_mfma_f32_16x16x32_bf16(aF[rt][kc], bF, aG[rt], 0,0,0);
        }
        float bv = bl[n], bgv = blg[n];
        #pragma unroll
        for (int rt=0; rt<4; ++rt){
            unsigned short pk[4];
            #pragma unroll
            for (int r=0; r<4; ++r){
                float mk = mask_s[rt*16 + g*4 + r];
                pk[r] = f2b((aV[rt][r] + bv)*mk * sigm(aG[rt][r] + bgv));
            }
            *(ushort4*)&lds_l[n][rt*16 + g*4] = make_ushort4(pk[0],pk[1],pk[2],pk[3]);
        }
    }
    // Pass R: mats 1 (Wr), 3 (Wrg)
    {
        f32x4 aV[4] = {{0,0,0,0},{0,0,0,0},{0,0,0,0},{0,0,0,0}};
        f32x4 aG[4] = {{0,0,0,0},{0,0,0,0},{0,0,0,0},{0,0,0,0}};
        #pragma unroll
        for (int kc=0; kc<4; ++kc){
            short8 bF = *(const short8*)&WTf[(((1*8 + wv)*4 + kc) << 9) + lane*8];
            #pragma unroll
            for (int rt=0; rt<4; ++rt)
                aV[rt] = __builtin_amdgcn_mfma_f32_16x16x32_bf16(aF[rt][kc], bF, aV[rt], 0,0,0);
        }
        #pragma unroll
        for (int kc=0; kc<4; ++kc){
            short8 bF = *(const short8*)&WTf[(((3*8 + wv)*4 + kc) << 9) + lane*8];
            #pragma unroll
            for (int rt=0; rt<4; ++rt)
                aG[rt] = __builtin_amdgcn_mfma_f32_16x16x32_bf16(aF[rt][kc], bF, aG[rt], 0,0,0);
        }
        float bv = br[n], bgv = brg[n];
        #pragma unroll
        for (int rt=0; rt<4; ++rt){
            unsigned short pk[4];
            #pragma unroll
            for (int r=0; r<4; ++r){
                float mk = mask_s[rt*16 + g*4 + r];
                pk[r] = f2b((aV[rt][r] + bv)*mk * sigm(aG[rt][r] + bgv));
            }
            *(ushort4*)&lds_r[n][rt*16 + g*4] = make_ushort4(pk[0],pk[1],pk[2],pk[3]);
        }
    }
    // Pass G: mat 4 (Wog) -> og_s (aliased onto xn_s)
    {
        f32x4 aV[4] = {{0,0,0,0},{0,0,0,0},{0,0,0,0},{0,0,0,0}};
        #pragma unroll
        for (int kc=0; kc<4; ++kc){
            short8 bF = *(const short8*)&WTf[(((4*8 + wv)*4 + kc) << 9) + lane*8];
            #pragma unroll
            for (int rt=0; rt<4; ++rt)
                aV[rt] = __builtin_amdgcn_mfma_f32_16x16x32_bf16(aF[rt][kc], bF, aV[rt], 0,0,0);
        }
        float bgv = bog[n];
        #pragma unroll
        for (int rt=0; rt<4; ++rt)
            #pragma unroll
            for (int r=0; r<4; ++r)
                xn_s[rt*16 + g*4 + r][n] = f2b(sigm(aV[rt][r] + bgv));
    }
    __syncthreads();

    // Phase C: coalesced writeouts (each n-row: 64 p els = 128B by 4 threads)
    {
        int nn = tid >> 2, quad = tid & 3;
        long gbase = (((long)(b*Nn + q))*Dn + nn)*Nn + p0 + quad*16;
        *(short8*)&leftT [gbase]     = *(const short8*)&lds_l[nn][quad*16];
        *(short8*)&leftT [gbase + 8] = *(const short8*)&lds_l[nn][quad*16 + 8];
        *(short8*)&rightT[gbase]     = *(const short8*)&lds_r[nn][quad*16];
        *(short8*)&rightT[gbase + 8] = *(const short8*)&lds_r[nn][quad*16 + 8];
    }
    {
        int row = tid >> 3, seg = tid & 7;   // 64 rows x 8 segs x 2x16B = 128 els
        long grow = ((long)(b*Nn + p0 + row))*Nn + q;
        *(short8*)&og[grow*256 + seg*16]     = *(const short8*)&xn_s[row][seg*16];
        *(short8*)&og[grow*256 + seg*16 + 8] = *(const short8*)&xn_s[row][seg*16 + 8];
    }
}

// ---------------------------------------------------------------------------
// K2: triangle einsum via MFMA. 1-D grid of 512, XCD-chunked swizzle:
// dispatch f -> logical L=(f%8)*64+f/8 so all 16 xy-blocks of a (b,db)
// z-slice land on ONE XCD. Block = 64i x 64j x 8d (one d per wave,
// per-wave-private LDS tiles), register staging, no K-loop barriers.
// Output tri[b][db][i][dd][j] bf16 via XOR-swizzled LDS transpose.
// ---------------------------------------------------------------------------
__global__ __launch_bounds__(512, 2) void k2_tri(
    const unsigned short* __restrict__ leftT, const unsigned short* __restrict__ rightT,
    unsigned short* __restrict__ tri)
{
    __shared__ __align__(16) char smem[65536];
    unsigned short (*l_s)[64][32] = (unsigned short(*)[64][32])smem;            // [8][64][32]
    unsigned short (*r_s)[64][32] = (unsigned short(*)[64][32])(smem + 32768);

    const int tid = threadIdx.x;
    const int wv = tid>>6, lane = tid&63;
    int f = blockIdx.x;
    int L = (f & 7)*64 + (f >> 3);
    int z = L >> 4, rem = L & 15;
    const int j0 = (rem & 3) * 64, i0 = (rem >> 2) * 64;
    const int db = z & 15, b = z >> 4;
    const int d  = db*8 + wv;
    const int l15 = lane&15, g = lane>>4;

    long rbaseL[4], rbaseR[4];
    int choff[4];
    #pragma unroll
    for (int jj=0; jj<4; ++jj){
        int slot = jj*64 + lane;
        int row = slot >> 2, ch = slot & 3;
        rbaseL[jj] = ((long)((b*Nn + j0 + row)*Dn + d)) << 8;
        rbaseR[jj] = ((long)((b*Nn + i0 + row)*Dn + d)) << 8;
        choff[jj] = ch*8;
    }
    short8* dl = (short8*)&l_s[wv][0][0];
    short8* dr = (short8*)&r_s[wv][0][0];

    f32x4 acc[4][4];
    #pragma unroll
    for (int a=0;a<4;++a)
        #pragma unroll
        for (int c=0;c<4;++c) acc[a][c] = (f32x4){0.f,0.f,0.f,0.f};

    for (int k0 = 0; k0 < Nn; k0 += 32){
        short8 stg[8];
        #pragma unroll
        for (int jj=0; jj<4; ++jj){
            stg[jj]   = *(const short8*)&leftT [rbaseL[jj] + k0 + choff[jj]];
            stg[4+jj] = *(const short8*)&rightT[rbaseR[jj] + k0 + choff[jj]];
        }
        #pragma unroll
        for (int jj=0; jj<4; ++jj){
            int slot = jj*64 + lane;
            dl[slot] = stg[jj];
            dr[slot] = stg[4+jj];
        }
        short8 aF[4];
        #pragma unroll
        for (int jt=0;jt<4;++jt) aF[jt] = *(const short8*)&l_s[wv][jt*16 + l15][g*8];
        #pragma unroll
        for (int it2=0;it2<4;++it2){
            short8 bF = *(const short8*)&r_s[wv][it2*16 + l15][g*8];
            #pragma unroll
            for (int jt=0;jt<4;++jt)
                acc[jt][it2] = __builtin_amdgcn_mfma_f32_16x16x32_bf16(aF[jt], bF, acc[jt][it2], 0,0,0);
        }
    }
    __syncthreads();

    unsigned short* tsb = (unsigned short*)smem;
    #pragma unroll
    for (int jt=0;jt<4;++jt){
        #pragma unroll
        for (int it2=0;it2<4;++it2){
            int iloc = it2*16 + l15;
            int rowid = iloc*8 + wv;
            int slotw = (2*jt + (g>>1)) ^ (iloc & 7);
            ushort4 v = make_ushort4(f2b(acc[jt][it2][0]), f2b(acc[jt][it2][1]),
                                     f2b(acc[jt][it2][2]), f2b(acc[jt][it2][3]));
            *(ushort4*)&tsb[rowid*64 + slotw*8 + (g&1)*4] = v;
        }
    }
    __syncthreads();

    long gb = ((((long)(b*16+db))*Nn + i0)*8)*Nn + j0;
    #pragma unroll
    for (int itr=0; itr<8; ++itr){
        int rowid = itr*64 + (tid>>3);
        int jseg  = tid & 7;
        int i_loc = rowid >> 3;
        short8 val = *(const short8*)&tsb[rowid*64 + ((jseg ^ (i_loc&7))*8)];
        *(short8*)&tri[gb + (long)rowid*Nn + jseg*8] = val;
    }
}

// ---------------------------------------------------------------------------
// K3: LN2 + out-gate + final GEMM (MFMA).  Block = 32 rows (b, i, j0..j0+32).
// og read bf16 from d_out (512B/row stride), final out written over it
// in place (same rows, read-before-write, barrier-ordered).
// ---------------------------------------------------------------------------
__global__ __launch_bounds__(256, 3) void k3_out(
    const unsigned short* __restrict__ tri, const unsigned short* __restrict__ ogu,
    const float* __restrict__ g2, const float* __restrict__ b2,
    const unsigned short* __restrict__ WTf, const float* __restrict__ bo,
    float* __restrict__ out)
{
    __shared__ __align__(16) unsigned short trn_s[32][136];
    __shared__ __align__(16) unsigned short xn_s[32][160];
    __shared__ __align__(16) float out_s[32][132];

    const int tid = threadIdx.x;
    int bid = blockIdx.x;
    int jb = bid & 7, i = (bid>>3) & 255, b = bid >> 11;
    int j0 = jb*32;

    {
        int dfull = tid >> 1, jh = tid & 1;
        int db = dfull >> 3, dd = dfull & 7;
        long base = ((((long)(b*16+db))*Nn + i)*8 + dd)*Nn + j0 + jh*16;
        union { short8 s8[2]; unsigned short u[16]; } v;
        v.s8[0] = *(const short8*)&tri[base];
        v.s8[1] = *(const short8*)&tri[base+8];
        #pragma unroll
        for (int jj=0;jj<16;++jj) trn_s[jh*16+jj][dfull] = v.u[jj];
    }
    __syncthreads();

    const int wv = tid>>6, lane = tid&63;
    #pragma unroll
    for (int rr=0; rr<8; ++rr){
        int r = wv*8 + rr;
        float v0 = b2f(trn_s[r][lane]), v1 = b2f(trn_s[r][lane+64]);
        float s = v0+v1, sq = v0*v0+v1*v1;
        #pragma unroll
        for (int m=1; m<64; m<<=1){ s += __shfl_xor(s,m); sq += __shfl_xor(sq,m); }
        float mean = s*(1.f/128.f);
        float var  = sq*(1.f/128.f) - mean*mean;
        float rstd = rsqrtf(var + 1e-5f);
        long grow = ((long)(b*Nn + i))*Nn + j0 + r;
        float o0 = b2f(ogu[grow*256 + lane]);
        float o1 = b2f(ogu[grow*256 + lane + 64]);
        xn_s[r][lane]    = f2b(((v0-mean)*rstd*g2[lane]    + b2[lane])   *o0);
        xn_s[r][lane+64] = f2b(((v1-mean)*rstd*g2[lane+64] + b2[lane+64])*o1);
    }
    __syncthreads();

    const int l15 = lane&15, g = lane>>4;
    const int it = wv>>1, nh = wv&1;
    short8 aF[4];
    #pragma unroll
    for (int kc=0; kc<4; ++kc)
        aF[kc] = *(const short8*)&xn_s[it*16 + l15][kc*32 + g*8];
    #pragma unroll
    for (int nt=0; nt<4; ++nt){
        int n0 = nh*64 + nt*16;
        f32x4 c = {0.f,0.f,0.f,0.f};
        #pragma unroll
        for (int kc=0; kc<4; ++kc){
            short8 bF = *(const short8*)&WTf[(((40 + nh*4 + nt)*4 + kc) << 9) + lane*8];
            c = __builtin_amdgcn_mfma_f32_16x16x32_bf16(aF[kc], bF, c, 0,0,0);
        }
        float bov = bo[n0 + l15];
        #pragma unroll
        for (int r=0;r<4;++r)
            out_s[it*16 + g*4 + r][n0 + l15] = c[r] + bov;
    }
    __syncthreads();

    {
        int row = tid>>3, seg = tid&7;
        long grow = ((long)(b*Nn + i))*Nn + j0 + row;
        #pragma unroll
        for (int e=0;e<4;++e){
            f32x4 v = *(f32x4*)&out_s[row][seg*16 + e*4];
            *(f32x4*)&out[grow*Dn + seg*16 + e*4] = v;
        }
    }
}

extern "C" void kernel_launch(void* const* d_in, const int* in_sizes, int n_in,
                              void* d_out, int out_size, void* d_ws, size_t ws_size,
                              hipStream_t stream)
{
    const float* x   = (const float*)d_in[0];
    const int*   msk = (const int*)  d_in[1];
    const float* g1  = (const float*)d_in[2];
    const float* b1  = (const float*)d_in[3];
    const float* Wl  = (const float*)d_in[4];
    const float* bl  = (const float*)d_in[5];
    const float* Wr  = (const float*)d_in[6];
    const float* br  = (const float*)d_in[7];
    const float* Wlg = (const float*)d_in[8];
    const float* blg = (const float*)d_in[9];
    const float* Wrg = (const float*)d_in[10];
    const float* brg = (const float*)d_in[11];
    const float* Wog = (const float*)d_in[12];
    const float* bog = (const float*)d_in[13];
    const float* g2  = (const float*)d_in[14];
    const float* b2  = (const float*)d_in[15];
    const float* Wo  = (const float*)d_in[16];
    const float* bo  = (const float*)d_in[17];

    float* out = (float*)d_out;
    unsigned short* ogu = (unsigned short*)d_out;   // bf16 gate @ 512B/row stride
    char* wsb = (char*)d_ws;
    unsigned short* leftT  = (unsigned short*)wsb;                    // 32 MB
    unsigned short* rightT = (unsigned short*)(wsb + 33554432);       // 32 MB
    unsigned short* tri    = (unsigned short*)(wsb + 67108864);       // 32 MB
    unsigned short* WTf    = (unsigned short*)(wsb + 100663296);      // 192 KB

    hipLaunchKernelGGL(k0_wt, dim3(48), dim3(256), 0, stream,
                       Wl, Wr, Wlg, Wrg, Wog, Wo, WTf);
    hipLaunchKernelGGL(k1_proj, dim3(Bn*Nn*4), dim3(512), 0, stream,
                       x, msk, g1, b1, WTf, bl, br, blg, brg, bog,
                       leftT, rightT, ogu);
    hipLaunchKernelGGL(k2_tri, dim3(512), dim3(512), 0, stream,
                       leftT, rightT, tri);
    hipLaunchKernelGGL(k3_out, dim3(Bn*Nn*8), dim3(256), 0, stream,
                       tri, ogu, g2, b2, WTf, bo, out);
}

// Round 11
// 132.576 us; speedup vs baseline: 1.0205x; 1.0205x over previous
//
#include <hip/hip_runtime.h>
#include <hip/hip_bf16.h>
#include <stdint.h>

#define Bn 2
#define Nn 256
#define Dn 128

typedef __attribute__((ext_vector_type(8))) short short8;
typedef __attribute__((ext_vector_type(4))) float f32x4;

__device__ __forceinline__ float sigm(float x){
    return __builtin_amdgcn_rcpf(1.0f + __builtin_amdgcn_exp2f(-1.44269504f*x));
}
__device__ __forceinline__ unsigned short f2b(float f){
    __hip_bfloat16 h = __float2bfloat16(f);
    return __builtin_bit_cast(unsigned short, h);
}
__device__ __forceinline__ float b2f(unsigned short h){
    return __uint_as_float(((unsigned)h)<<16);
}

// ---------------------------------------------------------------------------
// K0: W[k][n] fp32 -> WTf in MFMA B-fragment order:
//   frag f = (mat*8 + nt)*4 + kc ; lane l, elem e holds
//   W[k = kc*32 + (l>>4)*8 + e][n = nt*16 + (l&15)]
// mats: 0=Wl 1=Wr 2=Wlg 3=Wrg 4=Wog 5=Wo
// ---------------------------------------------------------------------------
__global__ __launch_bounds__(256) void k0_wt(
    const float* __restrict__ Wl, const float* __restrict__ Wr,
    const float* __restrict__ Wlg, const float* __restrict__ Wrg,
    const float* __restrict__ Wog, const float* __restrict__ Wo,
    unsigned short* __restrict__ WTf)
{
    int mat = blockIdx.x >> 3, nt = blockIdx.x & 7;
    const float* W = (mat==0)?Wl:(mat==1)?Wr:(mat==2)?Wlg:(mat==3)?Wrg:(mat==4)?Wog:Wo;
    int t = threadIdx.x;
    int kc = t >> 6, l = t & 63;
    int n  = nt*16 + (l & 15);
    int k0 = kc*32 + (l >> 4)*8;
    short8 sv;
    #pragma unroll
    for (int e=0;e<8;++e) sv[e] = (short)f2b(W[(k0+e)*128 + n]);
    *(short8*)&WTf[(((mat*8 + nt)*4 + kc) << 9) + l*8] = sv;
}

// ---------------------------------------------------------------------------
// K1: LN1 + 5 projections via MFMA.  R8 structure (32 rows/block, 4096 blocks,
// 512 threads / 8 waves, wave w owns 32 rows x 16 cols, 3 mat-pair passes,
// (512,6) no-spill) with ONE change vs R8: left/right stored DIRECTLY from
// accumulators (D-frag is p-contiguous per lane in leftT[b][q][n][p]) --
// deletes the lds_l/lds_r round-trip + one barrier; LDS 29.7->8.8 KB;
// stores drain during subsequent passes. og keeps LDS transpose (n-innermost
// layout would scatter) and lands bf16 in d_out @512B/row (k3 in-place-safe).
// ---------------------------------------------------------------------------
__global__ __launch_bounds__(512, 6) void k1_proj(
    const float* __restrict__ x, const int* __restrict__ msk,
    const float* __restrict__ g1, const float* __restrict__ b1,
    const unsigned short* __restrict__ WTf,
    const float* __restrict__ bl, const float* __restrict__ br,
    const float* __restrict__ blg, const float* __restrict__ brg,
    const float* __restrict__ bog,
    unsigned short* __restrict__ leftT, unsigned short* __restrict__ rightT,
    unsigned short* __restrict__ og)
{
    __shared__ __align__(16) unsigned short xn_s[32][136];   // reused as og_s later
    __shared__ float mask_s[32];

    const int tid = threadIdx.x;
    const int wv = tid>>6, lane = tid&63;
    int bid = blockIdx.x;
    int pb  = bid & 7;
    int q   = (bid >> 3) & 255;
    int b   = bid >> 11;
    int p0  = pb * 32;

    // Phase A: LN of 32 rows, 8 waves x 4 rows; x-loads batched up front
    {
        float a0[4], a1[4];
        #pragma unroll
        for (int rr=0; rr<4; ++rr){
            int r = wv*4 + rr;
            long row = ((long)(b*Nn + p0 + r))*Nn + q;
            const float* xr = x + row*Dn;
            a0[rr] = xr[lane]; a1[rr] = xr[lane+64];
        }
        if (lane < 4){
            int r = wv*4 + lane;
            mask_s[r] = (float)(msk[b*Nn + p0 + r] * msk[b*Nn + q]);
        }
        #pragma unroll
        for (int rr=0; rr<4; ++rr){
            int r = wv*4 + rr;
            float s = a0[rr]+a1[rr], sq = a0[rr]*a0[rr] + a1[rr]*a1[rr];
            #pragma unroll
            for (int m=1; m<64; m<<=1){ s += __shfl_xor(s,m); sq += __shfl_xor(sq,m); }
            float mean = s*(1.f/128.f);
            float var  = sq*(1.f/128.f) - mean*mean;
            float rstd = rsqrtf(var + 1e-5f);
            xn_s[r][lane]    = f2b((a0[rr]-mean)*rstd*g1[lane]    + b1[lane]);
            xn_s[r][lane+64] = f2b((a1[rr]-mean)*rstd*g1[lane+64] + b1[lane+64]);
        }
    }
    __syncthreads();

    const int l15 = lane & 15, g = lane >> 4;
    const int n = wv*16 + l15;
    const long gnL = (((long)(b*Nn + q))*Dn + n)*Nn + p0;   // col-n row base

    // A-frags: 2 row-tiles x 4 k-chunks (held across passes)
    short8 aF[2][4];
    #pragma unroll
    for (int rt=0; rt<2; ++rt)
        #pragma unroll
        for (int kc=0; kc<4; ++kc)
            aF[rt][kc] = *(const short8*)&xn_s[rt*16 + l15][kc*32 + g*8];
    __syncthreads();   // all aF reads done -> xn_s reusable as og_s

    // Pass L: mats 0 (Wl), 2 (Wlg) -> direct store to leftT
    {
        f32x4 aV[2] = {{0,0,0,0},{0,0,0,0}};
        f32x4 aG[2] = {{0,0,0,0},{0,0,0,0}};
        #pragma unroll
        for (int kc=0; kc<4; ++kc){
            short8 bF = *(const short8*)&WTf[(((0*8 + wv)*4 + kc) << 9) + lane*8];
            aV[0] = __builtin_amdgcn_mfma_f32_16x16x32_bf16(aF[0][kc], bF, aV[0], 0,0,0);
            aV[1] = __builtin_amdgcn_mfma_f32_16x16x32_bf16(aF[1][kc], bF, aV[1], 0,0,0);
        }
        #pragma unroll
        for (int kc=0; kc<4; ++kc){
            short8 bF = *(const short8*)&WTf[(((2*8 + wv)*4 + kc) << 9) + lane*8];
            aG[0] = __builtin_amdgcn_mfma_f32_16x16x32_bf16(aF[0][kc], bF, aG[0], 0,0,0);
            aG[1] = __builtin_amdgcn_mfma_f32_16x16x32_bf16(aF[1][kc], bF, aG[1], 0,0,0);
        }
        float bv = bl[n], bgv = blg[n];
        #pragma unroll
        for (int rt=0; rt<2; ++rt){
            unsigned short pk[4];
            #pragma unroll
            for (int r=0; r<4; ++r){
                float mk = mask_s[rt*16 + g*4 + r];
                pk[r] = f2b((aV[rt][r] + bv)*mk * sigm(aG[rt][r] + bgv));
            }
            *(ushort4*)&leftT[gnL + rt*16 + g*4] = make_ushort4(pk[0],pk[1],pk[2],pk[3]);
        }
    }
    // Pass R: mats 1 (Wr), 3 (Wrg) -> direct store to rightT
    {
        f32x4 aV[2] = {{0,0,0,0},{0,0,0,0}};
        f32x4 aG[2] = {{0,0,0,0},{0,0,0,0}};
        #pragma unroll
        for (int kc=0; kc<4; ++kc){
            short8 bF = *(const short8*)&WTf[(((1*8 + wv)*4 + kc) << 9) + lane*8];
            aV[0] = __builtin_amdgcn_mfma_f32_16x16x32_bf16(aF[0][kc], bF, aV[0], 0,0,0);
            aV[1] = __builtin_amdgcn_mfma_f32_16x16x32_bf16(aF[1][kc], bF, aV[1], 0,0,0);
        }
        #pragma unroll
        for (int kc=0; kc<4; ++kc){
            short8 bF = *(const short8*)&WTf[(((3*8 + wv)*4 + kc) << 9) + lane*8];
            aG[0] = __builtin_amdgcn_mfma_f32_16x16x32_bf16(aF[0][kc], bF, aG[0], 0,0,0);
            aG[1] = __builtin_amdgcn_mfma_f32_16x16x32_bf16(aF[1][kc], bF, aG[1], 0,0,0);
        }
        float bv = br[n], bgv = brg[n];
        #pragma unroll
        for (int rt=0; rt<2; ++rt){
            unsigned short pk[4];
            #pragma unroll
            for (int r=0; r<4; ++r){
                float mk = mask_s[rt*16 + g*4 + r];
                pk[r] = f2b((aV[rt][r] + bv)*mk * sigm(aG[rt][r] + bgv));
            }
            *(ushort4*)&rightT[gnL + rt*16 + g*4] = make_ushort4(pk[0],pk[1],pk[2],pk[3]);
        }
    }
    // Pass G: mat 4 (Wog) -> og_s (aliased onto xn_s)
    {
        f32x4 aV[2] = {{0,0,0,0},{0,0,0,0}};
        #pragma unroll
        for (int kc=0; kc<4; ++kc){
            short8 bF = *(const short8*)&WTf[(((4*8 + wv)*4 + kc) << 9) + lane*8];
            aV[0] = __builtin_amdgcn_mfma_f32_16x16x32_bf16(aF[0][kc], bF, aV[0], 0,0,0);
            aV[1] = __builtin_amdgcn_mfma_f32_16x16x32_bf16(aF[1][kc], bF, aV[1], 0,0,0);
        }
        float bgv = bog[n];
        #pragma unroll
        for (int rt=0; rt<2; ++rt)
            #pragma unroll
            for (int r=0; r<4; ++r)
                xn_s[rt*16 + g*4 + r][n] = f2b(sigm(aV[rt][r] + bgv));
    }
    __syncthreads();

    // og writeout: 32 rows x 16 segs x 8 els = 128 els/row
    {
        int row = tid >> 4, seg = tid & 15;
        long grow = ((long)(b*Nn + p0 + row))*Nn + q;
        *(short8*)&og[grow*256 + seg*8] = *(const short8*)&xn_s[row][seg*8];
    }
}

// ---------------------------------------------------------------------------
// K2: triangle einsum via MFMA. 1-D grid of 512, XCD-chunked swizzle:
// dispatch f -> logical L=(f%8)*64+f/8 so all 16 xy-blocks of a (b,db)
// z-slice land on ONE XCD. Block = 64i x 64j x 8d (one d per wave,
// per-wave-private LDS tiles), register staging, no K-loop barriers.
// Output tri[b][db][i][dd][j] bf16 via XOR-swizzled LDS transpose.
// ---------------------------------------------------------------------------
__global__ __launch_bounds__(512, 2) void k2_tri(
    const unsigned short* __restrict__ leftT, const unsigned short* __restrict__ rightT,
    unsigned short* __restrict__ tri)
{
    __shared__ __align__(16) char smem[65536];
    unsigned short (*l_s)[64][32] = (unsigned short(*)[64][32])smem;            // [8][64][32]
    unsigned short (*r_s)[64][32] = (unsigned short(*)[64][32])(smem + 32768);

    const int tid = threadIdx.x;
    const int wv = tid>>6, lane = tid&63;
    int f = blockIdx.x;
    int L = (f & 7)*64 + (f >> 3);
    int z = L >> 4, rem = L & 15;
    const int j0 = (rem & 3) * 64, i0 = (rem >> 2) * 64;
    const int db = z & 15, b = z >> 4;
    const int d  = db*8 + wv;
    const int l15 = lane&15, g = lane>>4;

    long rbaseL[4], rbaseR[4];
    int choff[4];
    #pragma unroll
    for (int jj=0; jj<4; ++jj){
        int slot = jj*64 + lane;
        int row = slot >> 2, ch = slot & 3;
        rbaseL[jj] = ((long)((b*Nn + j0 + row)*Dn + d)) << 8;
        rbaseR[jj] = ((long)((b*Nn + i0 + row)*Dn + d)) << 8;
        choff[jj] = ch*8;
    }
    short8* dl = (short8*)&l_s[wv][0][0];
    short8* dr = (short8*)&r_s[wv][0][0];

    f32x4 acc[4][4];
    #pragma unroll
    for (int a=0;a<4;++a)
        #pragma unroll
        for (int c=0;c<4;++c) acc[a][c] = (f32x4){0.f,0.f,0.f,0.f};

    for (int k0 = 0; k0 < Nn; k0 += 32){
        short8 stg[8];
        #pragma unroll
        for (int jj=0; jj<4; ++jj){
            stg[jj]   = *(const short8*)&leftT [rbaseL[jj] + k0 + choff[jj]];
            stg[4+jj] = *(const short8*)&rightT[rbaseR[jj] + k0 + choff[jj]];
        }
        #pragma unroll
        for (int jj=0; jj<4; ++jj){
            int slot = jj*64 + lane;
            dl[slot] = stg[jj];
            dr[slot] = stg[4+jj];
        }
        short8 aF[4];
        #pragma unroll
        for (int jt=0;jt<4;++jt) aF[jt] = *(const short8*)&l_s[wv][jt*16 + l15][g*8];
        #pragma unroll
        for (int it2=0;it2<4;++it2){
            short8 bF = *(const short8*)&r_s[wv][it2*16 + l15][g*8];
            #pragma unroll
            for (int jt=0;jt<4;++jt)
                acc[jt][it2] = __builtin_amdgcn_mfma_f32_16x16x32_bf16(aF[jt], bF, acc[jt][it2], 0,0,0);
        }
    }
    __syncthreads();

    unsigned short* tsb = (unsigned short*)smem;
    #pragma unroll
    for (int jt=0;jt<4;++jt){
        #pragma unroll
        for (int it2=0;it2<4;++it2){
            int iloc = it2*16 + l15;
            int rowid = iloc*8 + wv;
            int slotw = (2*jt + (g>>1)) ^ (iloc & 7);
            ushort4 v = make_ushort4(f2b(acc[jt][it2][0]), f2b(acc[jt][it2][1]),
                                     f2b(acc[jt][it2][2]), f2b(acc[jt][it2][3]));
            *(ushort4*)&tsb[rowid*64 + slotw*8 + (g&1)*4] = v;
        }
    }
    __syncthreads();

    long gb = ((((long)(b*16+db))*Nn + i0)*8)*Nn + j0;
    #pragma unroll
    for (int itr=0; itr<8; ++itr){
        int rowid = itr*64 + (tid>>3);
        int jseg  = tid & 7;
        int i_loc = rowid >> 3;
        short8 val = *(const short8*)&tsb[rowid*64 + ((jseg ^ (i_loc&7))*8)];
        *(short8*)&tri[gb + (long)rowid*Nn + jseg*8] = val;
    }
}

// ---------------------------------------------------------------------------
// K3: LN2 + out-gate + final GEMM (MFMA).  Block = 32 rows (b, i, j0..j0+32).
// og read bf16 from d_out (512B/row stride), final out written over it
// in place (same rows, read-before-write, barrier-ordered).
// ---------------------------------------------------------------------------
__global__ __launch_bounds__(256, 3) void k3_out(
    const unsigned short* __restrict__ tri, const unsigned short* __restrict__ ogu,
    const float* __restrict__ g2, const float* __restrict__ b2,
    const unsigned short* __restrict__ WTf, const float* __restrict__ bo,
    float* __restrict__ out)
{
    __shared__ __align__(16) unsigned short trn_s[32][136];
    __shared__ __align__(16) unsigned short xn_s[32][160];
    __shared__ __align__(16) float out_s[32][132];

    const int tid = threadIdx.x;
    int bid = blockIdx.x;
    int jb = bid & 7, i = (bid>>3) & 255, b = bid >> 11;
    int j0 = jb*32;

    {
        int dfull = tid >> 1, jh = tid & 1;
        int db = dfull >> 3, dd = dfull & 7;
        long base = ((((long)(b*16+db))*Nn + i)*8 + dd)*Nn + j0 + jh*16;
        union { short8 s8[2]; unsigned short u[16]; } v;
        v.s8[0] = *(const short8*)&tri[base];
        v.s8[1] = *(const short8*)&tri[base+8];
        #pragma unroll
        for (int jj=0;jj<16;++jj) trn_s[jh*16+jj][dfull] = v.u[jj];
    }
    __syncthreads();

    const int wv = tid>>6, lane = tid&63;
    #pragma unroll
    for (int rr=0; rr<8; ++rr){
        int r = wv*8 + rr;
        float v0 = b2f(trn_s[r][lane]), v1 = b2f(trn_s[r][lane+64]);
        float s = v0+v1, sq = v0*v0+v1*v1;
        #pragma unroll
        for (int m=1; m<64; m<<=1){ s += __shfl_xor(s,m); sq += __shfl_xor(sq,m); }
        float mean = s*(1.f/128.f);
        float var  = sq*(1.f/128.f) - mean*mean;
        float rstd = rsqrtf(var + 1e-5f);
        long grow = ((long)(b*Nn + i))*Nn + j0 + r;
        float o0 = b2f(ogu[grow*256 + lane]);
        float o1 = b2f(ogu[grow*256 + lane + 64]);
        xn_s[r][lane]    = f2b(((v0-mean)*rstd*g2[lane]    + b2[lane])   *o0);
        xn_s[r][lane+64] = f2b(((v1-mean)*rstd*g2[lane+64] + b2[lane+64])*o1);
    }
    __syncthreads();

    const int l15 = lane&15, g = lane>>4;
    const int it = wv>>1, nh = wv&1;
    short8 aF[4];
    #pragma unroll
    for (int kc=0; kc<4; ++kc)
        aF[kc] = *(const short8*)&xn_s[it*16 + l15][kc*32 + g*8];
    #pragma unroll
    for (int nt=0; nt<4; ++nt){
        int n0 = nh*64 + nt*16;
        f32x4 c = {0.f,0.f,0.f,0.f};
        #pragma unroll
        for (int kc=0; kc<4; ++kc){
            short8 bF = *(const short8*)&WTf[(((40 + nh*4 + nt)*4 + kc) << 9) + lane*8];
            c = __builtin_amdgcn_mfma_f32_16x16x32_bf16(aF[kc], bF, c, 0,0,0);
        }
        float bov = bo[n0 + l15];
        #pragma unroll
        for (int r=0;r<4;++r)
            out_s[it*16 + g*4 + r][n0 + l15] = c[r] + bov;
    }
    __syncthreads();

    {
        int row = tid>>3, seg = tid&7;
        long grow = ((long)(b*Nn + i))*Nn + j0 + row;
        #pragma unroll
        for (int e=0;e<4;++e){
            f32x4 v = *(f32x4*)&out_s[row][seg*16 + e*4];
            *(f32x4*)&out[grow*Dn + seg*16 + e*4] = v;
        }
    }
}

extern "C" void kernel_launch(void* const* d_in, const int* in_sizes, int n_in,
                              void* d_out, int out_size, void* d_ws, size_t ws_size,
                              hipStream_t stream)
{
    const float* x   = (const float*)d_in[0];
    const int*   msk = (const int*)  d_in[1];
    const float* g1  = (const float*)d_in[2];
    const float* b1  = (const float*)d_in[3];
    const float* Wl  = (const float*)d_in[4];
    const float* bl  = (const float*)d_in[5];
    const float* Wr  = (const float*)d_in[6];
    const float* br  = (const float*)d_in[7];
    const float* Wlg = (const float*)d_in[8];
    const float* blg = (const float*)d_in[9];
    const float* Wrg = (const float*)d_in[10];
    const float* brg = (const float*)d_in[11];
    const float* Wog = (const float*)d_in[12];
    const float* bog = (const float*)d_in[13];
    const float* g2  = (const float*)d_in[14];
    const float* b2  = (const float*)d_in[15];
    const float* Wo  = (const float*)d_in[16];
    const float* bo  = (const float*)d_in[17];

    float* out = (float*)d_out;
    unsigned short* ogu = (unsigned short*)d_out;   // bf16 gate @ 512B/row stride
    char* wsb = (char*)d_ws;
    unsigned short* leftT  = (unsigned short*)wsb;                    // 32 MB
    unsigned short* rightT = (unsigned short*)(wsb + 33554432);       // 32 MB
    unsigned short* tri    = (unsigned short*)(wsb + 67108864);       // 32 MB
    unsigned short* WTf    = (unsigned short*)(wsb + 100663296);      // 192 KB

    hipLaunchKernelGGL(k0_wt, dim3(48), dim3(256), 0, stream,
                       Wl, Wr, Wlg, Wrg, Wog, Wo, WTf);
    hipLaunchKernelGGL(k1_proj, dim3(Bn*Nn*8), dim3(512), 0, stream,
                       x, msk, g1, b1, WTf, bl, br, blg, brg, bog,
                       leftT, rightT, ogu);
    hipLaunchKernelGGL(k2_tri, dim3(512), dim3(512), 0, stream,
                       leftT, rightT, tri);
    hipLaunchKernelGGL(k3_out, dim3(Bn*Nn*8), dim3(256), 0, stream,
                       tri, ogu, g2, b2, WTf, bo, out);
}

// Round 12
// 129.735 us; speedup vs baseline: 1.0429x; 1.0219x over previous
//
#include <hip/hip_runtime.h>
#include <hip/hip_bf16.h>
#include <stdint.h>

#define Bn 2
#define Nn 256
#define Dn 128

typedef __attribute__((ext_vector_type(8))) short short8;
typedef __attribute__((ext_vector_type(4))) float f32x4;

__device__ __forceinline__ float sigm(float x){
    return __builtin_amdgcn_rcpf(1.0f + __builtin_amdgcn_exp2f(-1.44269504f*x));
}
__device__ __forceinline__ unsigned short f2b(float f){
    __hip_bfloat16 h = __float2bfloat16(f);
    return __builtin_bit_cast(unsigned short, h);
}
__device__ __forceinline__ float b2f(unsigned short h){
    return __uint_as_float(((unsigned)h)<<16);
}

// ---------------------------------------------------------------------------
// K0: W[k][n] fp32 -> WTf in MFMA B-fragment order:
//   frag f = (mat*8 + nt)*4 + kc ; lane l, elem e holds
//   W[k = kc*32 + (l>>4)*8 + e][n = nt*16 + (l&15)]
// mats: 0=Wl 1=Wr 2=Wlg 3=Wrg 4=Wog 5=Wo
// ---------------------------------------------------------------------------
__global__ __launch_bounds__(256) void k0_wt(
    const float* __restrict__ Wl, const float* __restrict__ Wr,
    const float* __restrict__ Wlg, const float* __restrict__ Wrg,
    const float* __restrict__ Wog, const float* __restrict__ Wo,
    unsigned short* __restrict__ WTf)
{
    int mat = blockIdx.x >> 3, nt = blockIdx.x & 7;
    const float* W = (mat==0)?Wl:(mat==1)?Wr:(mat==2)?Wlg:(mat==3)?Wrg:(mat==4)?Wog:Wo;
    int t = threadIdx.x;
    int kc = t >> 6, l = t & 63;
    int n  = nt*16 + (l & 15);
    int k0 = kc*32 + (l >> 4)*8;
    short8 sv;
    #pragma unroll
    for (int e=0;e<8;++e) sv[e] = (short)f2b(W[(k0+e)*128 + n]);
    *(short8*)&WTf[(((mat*8 + nt)*4 + kc) << 9) + l*8] = sv;
}

// ---------------------------------------------------------------------------
// K1: LN1 + 5 projections via MFMA — EXACT R8 structure (73 us known-good;
// R10 64-row tile and R11 direct-store both regressed, so this is kept as
// the local optimum).  Block = 32 rows (b, p0..p0+32, q fixed), 512 thr /
// 8 waves, wave w owns 32 rows x 16 cols.  Mat-pair passes {Wl,Wlg} ->
// {Wr,Wrg} -> {Wog}, 16 AGPR peak.  (512,6): no spill.  LDS 29.7KB
// (og_s aliases xn_s after aF loads + barrier).  left/right staged through
// lds_l/lds_r for 16B/lane coalesced stores (direct 8B stores were WORSE,
// R11).  og bf16 in d_out @512B/row stride (in-place-safe for k3).
// ---------------------------------------------------------------------------
__global__ __launch_bounds__(512, 6) void k1_proj(
    const float* __restrict__ x, const int* __restrict__ msk,
    const float* __restrict__ g1, const float* __restrict__ b1,
    const unsigned short* __restrict__ WTf,
    const float* __restrict__ bl, const float* __restrict__ br,
    const float* __restrict__ blg, const float* __restrict__ brg,
    const float* __restrict__ bog,
    unsigned short* __restrict__ leftT, unsigned short* __restrict__ rightT,
    unsigned short* __restrict__ og)
{
    __shared__ __align__(16) unsigned short xn_s[32][136];   // reused as og_s later
    __shared__ __align__(16) unsigned short lds_l[128][40];
    __shared__ __align__(16) unsigned short lds_r[128][40];
    __shared__ float mask_s[32];

    const int tid = threadIdx.x;
    const int wv = tid>>6, lane = tid&63;
    int bid = blockIdx.x;
    int pb  = bid & 7;
    int q   = (bid >> 3) & 255;
    int b   = bid >> 11;
    int p0  = pb * 32;

    // Phase A: LN of 32 rows, 8 waves x 4 rows; all x-loads issued up front
    {
        float a0[4], a1[4];
        #pragma unroll
        for (int rr=0; rr<4; ++rr){
            int r = wv*4 + rr;
            long row = ((long)(b*Nn + p0 + r))*Nn + q;
            const float* xr = x + row*Dn;
            a0[rr] = xr[lane]; a1[rr] = xr[lane+64];
        }
        if (lane < 4){
            int r = wv*4 + lane;
            mask_s[r] = (float)(msk[b*Nn + p0 + r] * msk[b*Nn + q]);
        }
        #pragma unroll
        for (int rr=0; rr<4; ++rr){
            int r = wv*4 + rr;
            float s = a0[rr]+a1[rr], sq = a0[rr]*a0[rr] + a1[rr]*a1[rr];
            #pragma unroll
            for (int m=1; m<64; m<<=1){ s += __shfl_xor(s,m); sq += __shfl_xor(sq,m); }
            float mean = s*(1.f/128.f);
            float var  = sq*(1.f/128.f) - mean*mean;
            float rstd = rsqrtf(var + 1e-5f);
            xn_s[r][lane]    = f2b((a0[rr]-mean)*rstd*g1[lane]    + b1[lane]);
            xn_s[r][lane+64] = f2b((a1[rr]-mean)*rstd*g1[lane+64] + b1[lane+64]);
        }
    }
    __syncthreads();

    const int l15 = lane & 15, g = lane >> 4;
    const int n = wv*16 + l15;

    // A-frags: 2 row-tiles x 4 k-chunks (held across passes)
    short8 aF[2][4];
    #pragma unroll
    for (int rt=0; rt<2; ++rt)
        #pragma unroll
        for (int kc=0; kc<4; ++kc)
            aF[rt][kc] = *(const short8*)&xn_s[rt*16 + l15][kc*32 + g*8];
    __syncthreads();   // all aF reads done -> xn_s reusable as og_s

    // Pass L: mats 0 (Wl), 2 (Wlg)
    {
        f32x4 aV[2] = {{0,0,0,0},{0,0,0,0}};
        f32x4 aG[2] = {{0,0,0,0},{0,0,0,0}};
        #pragma unroll
        for (int kc=0; kc<4; ++kc){
            short8 bF = *(const short8*)&WTf[(((0*8 + wv)*4 + kc) << 9) + lane*8];
            aV[0] = __builtin_amdgcn_mfma_f32_16x16x32_bf16(aF[0][kc], bF, aV[0], 0,0,0);
            aV[1] = __builtin_amdgcn_mfma_f32_16x16x32_bf16(aF[1][kc], bF, aV[1], 0,0,0);
        }
        #pragma unroll
        for (int kc=0; kc<4; ++kc){
            short8 bF = *(const short8*)&WTf[(((2*8 + wv)*4 + kc) << 9) + lane*8];
            aG[0] = __builtin_amdgcn_mfma_f32_16x16x32_bf16(aF[0][kc], bF, aG[0], 0,0,0);
            aG[1] = __builtin_amdgcn_mfma_f32_16x16x32_bf16(aF[1][kc], bF, aG[1], 0,0,0);
        }
        float bv = bl[n], bgv = blg[n];
        #pragma unroll
        for (int rt=0; rt<2; ++rt){
            unsigned short pk[4];
            #pragma unroll
            for (int r=0; r<4; ++r){
                float mk = mask_s[rt*16 + g*4 + r];
                pk[r] = f2b((aV[rt][r] + bv)*mk * sigm(aG[rt][r] + bgv));
            }
            *(ushort4*)&lds_l[n][rt*16 + g*4] = make_ushort4(pk[0],pk[1],pk[2],pk[3]);
        }
    }
    // Pass R: mats 1 (Wr), 3 (Wrg)
    {
        f32x4 aV[2] = {{0,0,0,0},{0,0,0,0}};
        f32x4 aG[2] = {{0,0,0,0},{0,0,0,0}};
        #pragma unroll
        for (int kc=0; kc<4; ++kc){
            short8 bF = *(const short8*)&WTf[(((1*8 + wv)*4 + kc) << 9) + lane*8];
            aV[0] = __builtin_amdgcn_mfma_f32_16x16x32_bf16(aF[0][kc], bF, aV[0], 0,0,0);
            aV[1] = __builtin_amdgcn_mfma_f32_16x16x32_bf16(aF[1][kc], bF, aV[1], 0,0,0);
        }
        #pragma unroll
        for (int kc=0; kc<4; ++kc){
            short8 bF = *(const short8*)&WTf[(((3*8 + wv)*4 + kc) << 9) + lane*8];
            aG[0] = __builtin_amdgcn_mfma_f32_16x16x32_bf16(aF[0][kc], bF, aG[0], 0,0,0);
            aG[1] = __builtin_amdgcn_mfma_f32_16x16x32_bf16(aF[1][kc], bF, aG[1], 0,0,0);
        }
        float bv = br[n], bgv = brg[n];
        #pragma unroll
        for (int rt=0; rt<2; ++rt){
            unsigned short pk[4];
            #pragma unroll
            for (int r=0; r<4; ++r){
                float mk = mask_s[rt*16 + g*4 + r];
                pk[r] = f2b((aV[rt][r] + bv)*mk * sigm(aG[rt][r] + bgv));
            }
            *(ushort4*)&lds_r[n][rt*16 + g*4] = make_ushort4(pk[0],pk[1],pk[2],pk[3]);
        }
    }
    // Pass G: mat 4 (Wog) -> og_s (aliased onto xn_s)
    {
        f32x4 aV[2] = {{0,0,0,0},{0,0,0,0}};
        #pragma unroll
        for (int kc=0; kc<4; ++kc){
            short8 bF = *(const short8*)&WTf[(((4*8 + wv)*4 + kc) << 9) + lane*8];
            aV[0] = __builtin_amdgcn_mfma_f32_16x16x32_bf16(aF[0][kc], bF, aV[0], 0,0,0);
            aV[1] = __builtin_amdgcn_mfma_f32_16x16x32_bf16(aF[1][kc], bF, aV[1], 0,0,0);
        }
        float bgv = bog[n];
        #pragma unroll
        for (int rt=0; rt<2; ++rt)
            #pragma unroll
            for (int r=0; r<4; ++r)
                xn_s[rt*16 + g*4 + r][n] = f2b(sigm(aV[rt][r] + bgv));
    }
    __syncthreads();

    // Phase C: coalesced writeouts
    {
        int nn = tid >> 2, quad = tid & 3;
        long gbase = (((long)(b*Nn + q))*Dn + nn)*Nn + p0 + quad*8;
        *(short8*)&leftT [gbase] = *(const short8*)&lds_l[nn][quad*8];
        *(short8*)&rightT[gbase] = *(const short8*)&lds_r[nn][quad*8];
    }
    {
        int row = tid >> 4, seg = tid & 15;   // 32 rows x 16 segs x 8 els
        long grow = ((long)(b*Nn + p0 + row))*Nn + q;
        *(short8*)&og[grow*256 + seg*8] = *(const short8*)&xn_s[row][seg*8];
    }
}

// ---------------------------------------------------------------------------
// K2: triangle einsum via MFMA. 1-D grid of 512, XCD-chunked swizzle
// (L=(f%8)*64+f/8: all 16 xy-blocks of a (b,db) z-slice on ONE XCD).
// Block = 64i x 64j x 8d (one d per wave, per-wave-private LDS tiles),
// register staging with explicit 1-deep prefetch: iteration i+1's global
// loads issue before iteration i's MFMAs (per-wave in-order DS queue keeps
// the LDS WAR safe; no barriers in the K-loop).
// Output tri[b][db][i][dd][j] bf16 via XOR-swizzled LDS transpose.
// ---------------------------------------------------------------------------
__global__ __launch_bounds__(512, 2) void k2_tri(
    const unsigned short* __restrict__ leftT, const unsigned short* __restrict__ rightT,
    unsigned short* __restrict__ tri)
{
    __shared__ __align__(16) char smem[65536];
    unsigned short (*l_s)[64][32] = (unsigned short(*)[64][32])smem;            // [8][64][32]
    unsigned short (*r_s)[64][32] = (unsigned short(*)[64][32])(smem + 32768);

    const int tid = threadIdx.x;
    const int wv = tid>>6, lane = tid&63;
    int f = blockIdx.x;
    int L = (f & 7)*64 + (f >> 3);
    int z = L >> 4, rem = L & 15;
    const int j0 = (rem & 3) * 64, i0 = (rem >> 2) * 64;
    const int db = z & 15, b = z >> 4;
    const int d  = db*8 + wv;
    const int l15 = lane&15, g = lane>>4;

    long rbaseL[4], rbaseR[4];
    int choff[4];
    #pragma unroll
    for (int jj=0; jj<4; ++jj){
        int slot = jj*64 + lane;
        int row = slot >> 2, ch = slot & 3;
        rbaseL[jj] = ((long)((b*Nn + j0 + row)*Dn + d)) << 8;
        rbaseR[jj] = ((long)((b*Nn + i0 + row)*Dn + d)) << 8;
        choff[jj] = ch*8;
    }
    short8* dl = (short8*)&l_s[wv][0][0];
    short8* dr = (short8*)&r_s[wv][0][0];

    f32x4 acc[4][4];
    #pragma unroll
    for (int a=0;a<4;++a)
        #pragma unroll
        for (int c=0;c<4;++c) acc[a][c] = (f32x4){0.f,0.f,0.f,0.f};

    // prologue: loads for k0 = 0
    short8 stg[8];
    #pragma unroll
    for (int jj=0; jj<4; ++jj){
        stg[jj]   = *(const short8*)&leftT [rbaseL[jj] + choff[jj]];
        stg[4+jj] = *(const short8*)&rightT[rbaseR[jj] + choff[jj]];
    }

    #pragma unroll
    for (int k0 = 0; k0 < Nn; k0 += 32){
        // write current tile to this wave's private LDS region
        #pragma unroll
        for (int jj=0; jj<4; ++jj){
            int slot = jj*64 + lane;
            dl[slot] = stg[jj];
            dr[slot] = stg[4+jj];
        }
        // prefetch next tile (independent of the DS ops above)
        short8 nstg[8];
        if (k0 + 32 < Nn){
            #pragma unroll
            for (int jj=0; jj<4; ++jj){
                nstg[jj]   = *(const short8*)&leftT [rbaseL[jj] + (k0+32) + choff[jj]];
                nstg[4+jj] = *(const short8*)&rightT[rbaseR[jj] + (k0+32) + choff[jj]];
            }
        }
        short8 aF[4];
        #pragma unroll
        for (int jt=0;jt<4;++jt) aF[jt] = *(const short8*)&l_s[wv][jt*16 + l15][g*8];
        #pragma unroll
        for (int it2=0;it2<4;++it2){
            short8 bF = *(const short8*)&r_s[wv][it2*16 + l15][g*8];
            #pragma unroll
            for (int jt=0;jt<4;++jt)
                acc[jt][it2] = __builtin_amdgcn_mfma_f32_16x16x32_bf16(aF[jt], bF, acc[jt][it2], 0,0,0);
        }
        #pragma unroll
        for (int jj=0; jj<8; ++jj) stg[jj] = nstg[jj];
    }
    __syncthreads();

    unsigned short* tsb = (unsigned short*)smem;
    #pragma unroll
    for (int jt=0;jt<4;++jt){
        #pragma unroll
        for (int it2=0;it2<4;++it2){
            int iloc = it2*16 + l15;
            int rowid = iloc*8 + wv;
            int slotw = (2*jt + (g>>1)) ^ (iloc & 7);
            ushort4 v = make_ushort4(f2b(acc[jt][it2][0]), f2b(acc[jt][it2][1]),
                                     f2b(acc[jt][it2][2]), f2b(acc[jt][it2][3]));
            *(ushort4*)&tsb[rowid*64 + slotw*8 + (g&1)*4] = v;
        }
    }
    __syncthreads();

    long gb = ((((long)(b*16+db))*Nn + i0)*8)*Nn + j0;
    #pragma unroll
    for (int itr=0; itr<8; ++itr){
        int rowid = itr*64 + (tid>>3);
        int jseg  = tid & 7;
        int i_loc = rowid >> 3;
        short8 val = *(const short8*)&tsb[rowid*64 + ((jseg ^ (i_loc&7))*8)];
        *(short8*)&tri[gb + (long)rowid*Nn + jseg*8] = val;
    }
}

// ---------------------------------------------------------------------------
// K3: LN2 + out-gate + final GEMM (MFMA).  Block = 32 rows (b, i, j0..j0+32).
// og read bf16 from d_out (512B/row stride), final out written over it
// in place (same rows, read-before-write, barrier-ordered).
// ---------------------------------------------------------------------------
__global__ __launch_bounds__(256, 3) void k3_out(
    const unsigned short* __restrict__ tri, const unsigned short* __restrict__ ogu,
    const float* __restrict__ g2, const float* __restrict__ b2,
    const unsigned short* __restrict__ WTf, const float* __restrict__ bo,
    float* __restrict__ out)
{
    __shared__ __align__(16) unsigned short trn_s[32][136];
    __shared__ __align__(16) unsigned short xn_s[32][160];
    __shared__ __align__(16) float out_s[32][132];

    const int tid = threadIdx.x;
    int bid = blockIdx.x;
    int jb = bid & 7, i = (bid>>3) & 255, b = bid >> 11;
    int j0 = jb*32;

    {
        int dfull = tid >> 1, jh = tid & 1;
        int db = dfull >> 3, dd = dfull & 7;
        long base = ((((long)(b*16+db))*Nn + i)*8 + dd)*Nn + j0 + jh*16;
        union { short8 s8[2]; unsigned short u[16]; } v;
        v.s8[0] = *(const short8*)&tri[base];
        v.s8[1] = *(const short8*)&tri[base+8];
        #pragma unroll
        for (int jj=0;jj<16;++jj) trn_s[jh*16+jj][dfull] = v.u[jj];
    }
    __syncthreads();

    const int wv = tid>>6, lane = tid&63;
    #pragma unroll
    for (int rr=0; rr<8; ++rr){
        int r = wv*8 + rr;
        float v0 = b2f(trn_s[r][lane]), v1 = b2f(trn_s[r][lane+64]);
        float s = v0+v1, sq = v0*v0+v1*v1;
        #pragma unroll
        for (int m=1; m<64; m<<=1){ s += __shfl_xor(s,m); sq += __shfl_xor(sq,m); }
        float mean = s*(1.f/128.f);
        float var  = sq*(1.f/128.f) - mean*mean;
        float rstd = rsqrtf(var + 1e-5f);
        long grow = ((long)(b*Nn + i))*Nn + j0 + r;
        float o0 = b2f(ogu[grow*256 + lane]);
        float o1 = b2f(ogu[grow*256 + lane + 64]);
        xn_s[r][lane]    = f2b(((v0-mean)*rstd*g2[lane]    + b2[lane])   *o0);
        xn_s[r][lane+64] = f2b(((v1-mean)*rstd*g2[lane+64] + b2[lane+64])*o1);
    }
    __syncthreads();

    const int l15 = lane&15, g = lane>>4;
    const int it = wv>>1, nh = wv&1;
    short8 aF[4];
    #pragma unroll
    for (int kc=0; kc<4; ++kc)
        aF[kc] = *(const short8*)&xn_s[it*16 + l15][kc*32 + g*8];
    #pragma unroll
    for (int nt=0; nt<4; ++nt){
        int n0 = nh*64 + nt*16;
        f32x4 c = {0.f,0.f,0.f,0.f};
        #pragma unroll
        for (int kc=0; kc<4; ++kc){
            short8 bF = *(const short8*)&WTf[(((40 + nh*4 + nt)*4 + kc) << 9) + lane*8];
            c = __builtin_amdgcn_mfma_f32_16x16x32_bf16(aF[kc], bF, c, 0,0,0);
        }
        float bov = bo[n0 + l15];
        #pragma unroll
        for (int r=0;r<4;++r)
            out_s[it*16 + g*4 + r][n0 + l15] = c[r] + bov;
    }
    __syncthreads();

    {
        int row = tid>>3, seg = tid&7;
        long grow = ((long)(b*Nn + i))*Nn + j0 + row;
        #pragma unroll
        for (int e=0;e<4;++e){
            f32x4 v = *(f32x4*)&out_s[row][seg*16 + e*4];
            *(f32x4*)&out[grow*Dn + seg*16 + e*4] = v;
        }
    }
}

extern "C" void kernel_launch(void* const* d_in, const int* in_sizes, int n_in,
                              void* d_out, int out_size, void* d_ws, size_t ws_size,
                              hipStream_t stream)
{
    const float* x   = (const float*)d_in[0];
    const int*   msk = (const int*)  d_in[1];
    const float* g1  = (const float*)d_in[2];
    const float* b1  = (const float*)d_in[3];
    const float* Wl  = (const float*)d_in[4];
    const float* bl  = (const float*)d_in[5];
    const float* Wr  = (const float*)d_in[6];
    const float* br  = (const float*)d_in[7];
    const float* Wlg = (const float*)d_in[8];
    const float* blg = (const float*)d_in[9];
    const float* Wrg = (const float*)d_in[10];
    const float* brg = (const float*)d_in[11];
    const float* Wog = (const float*)d_in[12];
    const float* bog = (const float*)d_in[13];
    const float* g2  = (const float*)d_in[14];
    const float* b2  = (const float*)d_in[15];
    const float* Wo  = (const float*)d_in[16];
    const float* bo  = (const float*)d_in[17];

    float* out = (float*)d_out;
    unsigned short* ogu = (unsigned short*)d_out;   // bf16 gate @ 512B/row stride
    char* wsb = (char*)d_ws;
    unsigned short* leftT  = (unsigned short*)wsb;                    // 32 MB
    unsigned short* rightT = (unsigned short*)(wsb + 33554432);       // 32 MB
    unsigned short* tri    = (unsigned short*)(wsb + 67108864);       // 32 MB
    unsigned short* WTf    = (unsigned short*)(wsb + 100663296);      // 192 KB

    hipLaunchKernelGGL(k0_wt, dim3(48), dim3(256), 0, stream,
                       Wl, Wr, Wlg, Wrg, Wog, Wo, WTf);
    hipLaunchKernelGGL(k1_proj, dim3(Bn*Nn*8), dim3(512), 0, stream,
                       x, msk, g1, b1, WTf, bl, br, blg, brg, bog,
                       leftT, rightT, ogu);
    hipLaunchKernelGGL(k2_tri, dim3(512), dim3(512), 0, stream,
                       leftT, rightT, tri);
    hipLaunchKernelGGL(k3_out, dim3(Bn*Nn*8), dim3(256), 0, stream,
                       tri, ogu, g2, b2, WTf, bo, out);
}

// Round 13
// 121.281 us; speedup vs baseline: 1.1156x; 1.0697x over previous
//
#include <hip/hip_runtime.h>
#include <hip/hip_bf16.h>
#include <stdint.h>

#define Bn 2
#define Nn 256
#define Dn 128

typedef __attribute__((ext_vector_type(8))) short short8;
typedef __attribute__((ext_vector_type(4))) float f32x4;

__device__ __forceinline__ float sigm(float x){
    return __builtin_amdgcn_rcpf(1.0f + __builtin_amdgcn_exp2f(-1.44269504f*x));
}
__device__ __forceinline__ unsigned short f2b(float f){
    __hip_bfloat16 h = __float2bfloat16(f);
    return __builtin_bit_cast(unsigned short, h);
}
__device__ __forceinline__ float b2f(unsigned short h){
    return __uint_as_float(((unsigned)h)<<16);
}

// ---------------------------------------------------------------------------
// K0: W[k][n] fp32 -> WTf in MFMA B-fragment order:
//   frag f = (mat*8 + nt)*4 + kc ; lane l, elem e holds
//   W[k = kc*32 + (l>>4)*8 + e][n = nt*16 + (l&15)]
// mats: 0=Wl 1=Wr 2=Wlg 3=Wrg 4=Wog 5=Wo
// ---------------------------------------------------------------------------
__global__ __launch_bounds__(256) void k0_wt(
    const float* __restrict__ Wl, const float* __restrict__ Wr,
    const float* __restrict__ Wlg, const float* __restrict__ Wrg,
    const float* __restrict__ Wog, const float* __restrict__ Wo,
    unsigned short* __restrict__ WTf)
{
    int mat = blockIdx.x >> 3, nt = blockIdx.x & 7;
    const float* W = (mat==0)?Wl:(mat==1)?Wr:(mat==2)?Wlg:(mat==3)?Wrg:(mat==4)?Wog:Wo;
    int t = threadIdx.x;
    int kc = t >> 6, l = t & 63;
    int n  = nt*16 + (l & 15);
    int k0 = kc*32 + (l >> 4)*8;
    short8 sv;
    #pragma unroll
    for (int e=0;e<8;++e) sv[e] = (short)f2b(W[(k0+e)*128 + n]);
    *(short8*)&WTf[(((mat*8 + nt)*4 + kc) << 9) + l*8] = sv;
}

// ---------------------------------------------------------------------------
// K1: LN1 + 5 projections via MFMA.  R8/R12 phase structure, but targeting
// 4 blocks/CU: __launch_bounds__(512,8) with A-fragments RELOADED from xn_s
// per kc (short live range, ~35 peak regs) instead of held across passes
// (R7's spill cause under the 64-reg cap).  xn_s stays live all passes ->
// og_s is a separate buffer (no alias barrier); LDS 38.0KB x4 = 152 <= 160.
// Two barriers total.  left/right staged via lds_l/r for 16B/lane stores.
// og bf16 in d_out @512B/row stride (in-place-safe for k3).
// SPILL TELL: if FETCH/WRITE balloon vs 34/98MB -> revert to R12 k1.
// ---------------------------------------------------------------------------
__global__ __launch_bounds__(512, 8) void k1_proj(
    const float* __restrict__ x, const int* __restrict__ msk,
    const float* __restrict__ g1, const float* __restrict__ b1,
    const unsigned short* __restrict__ WTf,
    const float* __restrict__ bl, const float* __restrict__ br,
    const float* __restrict__ blg, const float* __restrict__ brg,
    const float* __restrict__ bog,
    unsigned short* __restrict__ leftT, unsigned short* __restrict__ rightT,
    unsigned short* __restrict__ og)
{
    __shared__ __align__(16) unsigned short xn_s[32][136];
    __shared__ __align__(16) unsigned short lds_l[128][40];
    __shared__ __align__(16) unsigned short lds_r[128][40];
    __shared__ __align__(16) unsigned short og_s[32][136];
    __shared__ float mask_s[32];

    const int tid = threadIdx.x;
    const int wv = tid>>6, lane = tid&63;
    int bid = blockIdx.x;
    int pb  = bid & 7;
    int q   = (bid >> 3) & 255;
    int b   = bid >> 11;
    int p0  = pb * 32;

    // Phase A: LN of 32 rows, 8 waves x 4 rows; x-loads batched up front
    {
        float a0[4], a1[4];
        #pragma unroll
        for (int rr=0; rr<4; ++rr){
            int r = wv*4 + rr;
            long row = ((long)(b*Nn + p0 + r))*Nn + q;
            const float* xr = x + row*Dn;
            a0[rr] = xr[lane]; a1[rr] = xr[lane+64];
        }
        if (lane < 4){
            int r = wv*4 + lane;
            mask_s[r] = (float)(msk[b*Nn + p0 + r] * msk[b*Nn + q]);
        }
        #pragma unroll
        for (int rr=0; rr<4; ++rr){
            int r = wv*4 + rr;
            float s = a0[rr]+a1[rr], sq = a0[rr]*a0[rr] + a1[rr]*a1[rr];
            #pragma unroll
            for (int m=1; m<64; m<<=1){ s += __shfl_xor(s,m); sq += __shfl_xor(sq,m); }
            float mean = s*(1.f/128.f);
            float var  = sq*(1.f/128.f) - mean*mean;
            float rstd = rsqrtf(var + 1e-5f);
            xn_s[r][lane]    = f2b((a0[rr]-mean)*rstd*g1[lane]    + b1[lane]);
            xn_s[r][lane+64] = f2b((a1[rr]-mean)*rstd*g1[lane+64] + b1[lane+64]);
        }
    }
    __syncthreads();

    const int l15 = lane & 15, g = lane >> 4;
    const int n = wv*16 + l15;

    // Pass L: mats 0 (Wl), 2 (Wlg) — aF reloaded per kc (short live range)
    {
        f32x4 aV[2] = {{0,0,0,0},{0,0,0,0}};
        f32x4 aG[2] = {{0,0,0,0},{0,0,0,0}};
        #pragma unroll
        for (int kc=0; kc<4; ++kc){
            short8 bF  = *(const short8*)&WTf[(((0*8 + wv)*4 + kc) << 9) + lane*8];
            short8 aF0 = *(const short8*)&xn_s[l15][kc*32 + g*8];
            short8 aF1 = *(const short8*)&xn_s[16 + l15][kc*32 + g*8];
            aV[0] = __builtin_amdgcn_mfma_f32_16x16x32_bf16(aF0, bF, aV[0], 0,0,0);
            aV[1] = __builtin_amdgcn_mfma_f32_16x16x32_bf16(aF1, bF, aV[1], 0,0,0);
        }
        #pragma unroll
        for (int kc=0; kc<4; ++kc){
            short8 bF  = *(const short8*)&WTf[(((2*8 + wv)*4 + kc) << 9) + lane*8];
            short8 aF0 = *(const short8*)&xn_s[l15][kc*32 + g*8];
            short8 aF1 = *(const short8*)&xn_s[16 + l15][kc*32 + g*8];
            aG[0] = __builtin_amdgcn_mfma_f32_16x16x32_bf16(aF0, bF, aG[0], 0,0,0);
            aG[1] = __builtin_amdgcn_mfma_f32_16x16x32_bf16(aF1, bF, aG[1], 0,0,0);
        }
        float bv = bl[n], bgv = blg[n];
        #pragma unroll
        for (int rt=0; rt<2; ++rt){
            unsigned short pk[4];
            #pragma unroll
            for (int r=0; r<4; ++r){
                float mk = mask_s[rt*16 + g*4 + r];
                pk[r] = f2b((aV[rt][r] + bv)*mk * sigm(aG[rt][r] + bgv));
            }
            *(ushort4*)&lds_l[n][rt*16 + g*4] = make_ushort4(pk[0],pk[1],pk[2],pk[3]);
        }
    }
    // Pass R: mats 1 (Wr), 3 (Wrg)
    {
        f32x4 aV[2] = {{0,0,0,0},{0,0,0,0}};
        f32x4 aG[2] = {{0,0,0,0},{0,0,0,0}};
        #pragma unroll
        for (int kc=0; kc<4; ++kc){
            short8 bF  = *(const short8*)&WTf[(((1*8 + wv)*4 + kc) << 9) + lane*8];
            short8 aF0 = *(const short8*)&xn_s[l15][kc*32 + g*8];
            short8 aF1 = *(const short8*)&xn_s[16 + l15][kc*32 + g*8];
            aV[0] = __builtin_amdgcn_mfma_f32_16x16x32_bf16(aF0, bF, aV[0], 0,0,0);
            aV[1] = __builtin_amdgcn_mfma_f32_16x16x32_bf16(aF1, bF, aV[1], 0,0,0);
        }
        #pragma unroll
        for (int kc=0; kc<4; ++kc){
            short8 bF  = *(const short8*)&WTf[(((3*8 + wv)*4 + kc) << 9) + lane*8];
            short8 aF0 = *(const short8*)&xn_s[l15][kc*32 + g*8];
            short8 aF1 = *(const short8*)&xn_s[16 + l15][kc*32 + g*8];
            aG[0] = __builtin_amdgcn_mfma_f32_16x16x32_bf16(aF0, bF, aG[0], 0,0,0);
            aG[1] = __builtin_amdgcn_mfma_f32_16x16x32_bf16(aF1, bF, aG[1], 0,0,0);
        }
        float bv = br[n], bgv = brg[n];
        #pragma unroll
        for (int rt=0; rt<2; ++rt){
            unsigned short pk[4];
            #pragma unroll
            for (int r=0; r<4; ++r){
                float mk = mask_s[rt*16 + g*4 + r];
                pk[r] = f2b((aV[rt][r] + bv)*mk * sigm(aG[rt][r] + bgv));
            }
            *(ushort4*)&lds_r[n][rt*16 + g*4] = make_ushort4(pk[0],pk[1],pk[2],pk[3]);
        }
    }
    // Pass G: mat 4 (Wog) -> og_s (separate buffer)
    {
        f32x4 aV[2] = {{0,0,0,0},{0,0,0,0}};
        #pragma unroll
        for (int kc=0; kc<4; ++kc){
            short8 bF  = *(const short8*)&WTf[(((4*8 + wv)*4 + kc) << 9) + lane*8];
            short8 aF0 = *(const short8*)&xn_s[l15][kc*32 + g*8];
            short8 aF1 = *(const short8*)&xn_s[16 + l15][kc*32 + g*8];
            aV[0] = __builtin_amdgcn_mfma_f32_16x16x32_bf16(aF0, bF, aV[0], 0,0,0);
            aV[1] = __builtin_amdgcn_mfma_f32_16x16x32_bf16(aF1, bF, aV[1], 0,0,0);
        }
        float bgv = bog[n];
        #pragma unroll
        for (int rt=0; rt<2; ++rt)
            #pragma unroll
            for (int r=0; r<4; ++r)
                og_s[rt*16 + g*4 + r][n] = f2b(sigm(aV[rt][r] + bgv));
    }
    __syncthreads();

    // Phase C: coalesced writeouts
    {
        int nn = tid >> 2, quad = tid & 3;
        long gbase = (((long)(b*Nn + q))*Dn + nn)*Nn + p0 + quad*8;
        *(short8*)&leftT [gbase] = *(const short8*)&lds_l[nn][quad*8];
        *(short8*)&rightT[gbase] = *(const short8*)&lds_r[nn][quad*8];
    }
    {
        int row = tid >> 4, seg = tid & 15;   // 32 rows x 16 segs x 8 els
        long grow = ((long)(b*Nn + p0 + row))*Nn + q;
        *(short8*)&og[grow*256 + seg*8] = *(const short8*)&og_s[row][seg*8];
    }
}

// ---------------------------------------------------------------------------
// K2: triangle einsum via MFMA. 1-D grid of 512, XCD-chunked swizzle
// (L=(f%8)*64+f/8: all 16 xy-blocks of a (b,db) z-slice on ONE XCD).
// Block = 64i x 64j x 8d (one d per wave, per-wave-private LDS tiles),
// register staging with 1-deep prefetch. No barriers in the K-loop.
// Output tri[b][db][i][dd][j] bf16 via XOR-swizzled LDS transpose.
// ---------------------------------------------------------------------------
__global__ __launch_bounds__(512, 2) void k2_tri(
    const unsigned short* __restrict__ leftT, const unsigned short* __restrict__ rightT,
    unsigned short* __restrict__ tri)
{
    __shared__ __align__(16) char smem[65536];
    unsigned short (*l_s)[64][32] = (unsigned short(*)[64][32])smem;            // [8][64][32]
    unsigned short (*r_s)[64][32] = (unsigned short(*)[64][32])(smem + 32768);

    const int tid = threadIdx.x;
    const int wv = tid>>6, lane = tid&63;
    int f = blockIdx.x;
    int L = (f & 7)*64 + (f >> 3);
    int z = L >> 4, rem = L & 15;
    const int j0 = (rem & 3) * 64, i0 = (rem >> 2) * 64;
    const int db = z & 15, b = z >> 4;
    const int d  = db*8 + wv;
    const int l15 = lane&15, g = lane>>4;

    long rbaseL[4], rbaseR[4];
    int choff[4];
    #pragma unroll
    for (int jj=0; jj<4; ++jj){
        int slot = jj*64 + lane;
        int row = slot >> 2, ch = slot & 3;
        rbaseL[jj] = ((long)((b*Nn + j0 + row)*Dn + d)) << 8;
        rbaseR[jj] = ((long)((b*Nn + i0 + row)*Dn + d)) << 8;
        choff[jj] = ch*8;
    }
    short8* dl = (short8*)&l_s[wv][0][0];
    short8* dr = (short8*)&r_s[wv][0][0];

    f32x4 acc[4][4];
    #pragma unroll
    for (int a=0;a<4;++a)
        #pragma unroll
        for (int c=0;c<4;++c) acc[a][c] = (f32x4){0.f,0.f,0.f,0.f};

    short8 stg[8];
    #pragma unroll
    for (int jj=0; jj<4; ++jj){
        stg[jj]   = *(const short8*)&leftT [rbaseL[jj] + choff[jj]];
        stg[4+jj] = *(const short8*)&rightT[rbaseR[jj] + choff[jj]];
    }

    #pragma unroll
    for (int k0 = 0; k0 < Nn; k0 += 32){
        #pragma unroll
        for (int jj=0; jj<4; ++jj){
            int slot = jj*64 + lane;
            dl[slot] = stg[jj];
            dr[slot] = stg[4+jj];
        }
        short8 nstg[8];
        if (k0 + 32 < Nn){
            #pragma unroll
            for (int jj=0; jj<4; ++jj){
                nstg[jj]   = *(const short8*)&leftT [rbaseL[jj] + (k0+32) + choff[jj]];
                nstg[4+jj] = *(const short8*)&rightT[rbaseR[jj] + (k0+32) + choff[jj]];
            }
        }
        short8 aF[4];
        #pragma unroll
        for (int jt=0;jt<4;++jt) aF[jt] = *(const short8*)&l_s[wv][jt*16 + l15][g*8];
        #pragma unroll
        for (int it2=0;it2<4;++it2){
            short8 bF = *(const short8*)&r_s[wv][it2*16 + l15][g*8];
            #pragma unroll
            for (int jt=0;jt<4;++jt)
                acc[jt][it2] = __builtin_amdgcn_mfma_f32_16x16x32_bf16(aF[jt], bF, acc[jt][it2], 0,0,0);
        }
        #pragma unroll
        for (int jj=0; jj<8; ++jj) stg[jj] = nstg[jj];
    }
    __syncthreads();

    unsigned short* tsb = (unsigned short*)smem;
    #pragma unroll
    for (int jt=0;jt<4;++jt){
        #pragma unroll
        for (int it2=0;it2<4;++it2){
            int iloc = it2*16 + l15;
            int rowid = iloc*8 + wv;
            int slotw = (2*jt + (g>>1)) ^ (iloc & 7);
            ushort4 v = make_ushort4(f2b(acc[jt][it2][0]), f2b(acc[jt][it2][1]),
                                     f2b(acc[jt][it2][2]), f2b(acc[jt][it2][3]));
            *(ushort4*)&tsb[rowid*64 + slotw*8 + (g&1)*4] = v;
        }
    }
    __syncthreads();

    long gb = ((((long)(b*16+db))*Nn + i0)*8)*Nn + j0;
    #pragma unroll
    for (int itr=0; itr<8; ++itr){
        int rowid = itr*64 + (tid>>3);
        int jseg  = tid & 7;
        int i_loc = rowid >> 3;
        short8 val = *(const short8*)&tsb[rowid*64 + ((jseg ^ (i_loc&7))*8)];
        *(short8*)&tri[gb + (long)rowid*Nn + jseg*8] = val;
    }
}

// ---------------------------------------------------------------------------
// K3: LN2 + out-gate + final GEMM (MFMA).  Block = 32 rows (b, i, j0..j0+32).
// og read bf16 from d_out (512B/row stride), final out written over it
// in place (same rows, read-before-write, barrier-ordered).
// ---------------------------------------------------------------------------
__global__ __launch_bounds__(256, 3) void k3_out(
    const unsigned short* __restrict__ tri, const unsigned short* __restrict__ ogu,
    const float* __restrict__ g2, const float* __restrict__ b2,
    const unsigned short* __restrict__ WTf, const float* __restrict__ bo,
    float* __restrict__ out)
{
    __shared__ __align__(16) unsigned short trn_s[32][136];
    __shared__ __align__(16) unsigned short xn_s[32][160];
    __shared__ __align__(16) float out_s[32][132];

    const int tid = threadIdx.x;
    int bid = blockIdx.x;
    int jb = bid & 7, i = (bid>>3) & 255, b = bid >> 11;
    int j0 = jb*32;

    {
        int dfull = tid >> 1, jh = tid & 1;
        int db = dfull >> 3, dd = dfull & 7;
        long base = ((((long)(b*16+db))*Nn + i)*8 + dd)*Nn + j0 + jh*16;
        union { short8 s8[2]; unsigned short u[16]; } v;
        v.s8[0] = *(const short8*)&tri[base];
        v.s8[1] = *(const short8*)&tri[base+8];
        #pragma unroll
        for (int jj=0;jj<16;++jj) trn_s[jh*16+jj][dfull] = v.u[jj];
    }
    __syncthreads();

    const int wv = tid>>6, lane = tid&63;
    #pragma unroll
    for (int rr=0; rr<8; ++rr){
        int r = wv*8 + rr;
        float v0 = b2f(trn_s[r][lane]), v1 = b2f(trn_s[r][lane+64]);
        float s = v0+v1, sq = v0*v0+v1*v1;
        #pragma unroll
        for (int m=1; m<64; m<<=1){ s += __shfl_xor(s,m); sq += __shfl_xor(sq,m); }
        float mean = s*(1.f/128.f);
        float var  = sq*(1.f/128.f) - mean*mean;
        float rstd = rsqrtf(var + 1e-5f);
        long grow = ((long)(b*Nn + i))*Nn + j0 + r;
        float o0 = b2f(ogu[grow*256 + lane]);
        float o1 = b2f(ogu[grow*256 + lane + 64]);
        xn_s[r][lane]    = f2b(((v0-mean)*rstd*g2[lane]    + b2[lane])   *o0);
        xn_s[r][lane+64] = f2b(((v1-mean)*rstd*g2[lane+64] + b2[lane+64])*o1);
    }
    __syncthreads();

    const int l15 = lane&15, g = lane>>4;
    const int it = wv>>1, nh = wv&1;
    short8 aF[4];
    #pragma unroll
    for (int kc=0; kc<4; ++kc)
        aF[kc] = *(const short8*)&xn_s[it*16 + l15][kc*32 + g*8];
    #pragma unroll
    for (int nt=0; nt<4; ++nt){
        int n0 = nh*64 + nt*16;
        f32x4 c = {0.f,0.f,0.f,0.f};
        #pragma unroll
        for (int kc=0; kc<4; ++kc){
            short8 bF = *(const short8*)&WTf[(((40 + nh*4 + nt)*4 + kc) << 9) + lane*8];
            c = __builtin_amdgcn_mfma_f32_16x16x32_bf16(aF[kc], bF, c, 0,0,0);
        }
        float bov = bo[n0 + l15];
        #pragma unroll
        for (int r=0;r<4;++r)
            out_s[it*16 + g*4 + r][n0 + l15] = c[r] + bov;
    }
    __syncthreads();

    {
        int row = tid>>3, seg = tid&7;
        long grow = ((long)(b*Nn + i))*Nn + j0 + row;
        #pragma unroll
        for (int e=0;e<4;++e){
            f32x4 v = *(f32x4*)&out_s[row][seg*16 + e*4];
            *(f32x4*)&out[grow*Dn + seg*16 + e*4] = v;
        }
    }
}

extern "C" void kernel_launch(void* const* d_in, const int* in_sizes, int n_in,
                              void* d_out, int out_size, void* d_ws, size_t ws_size,
                              hipStream_t stream)
{
    const float* x   = (const float*)d_in[0];
    const int*   msk = (const int*)  d_in[1];
    const float* g1  = (const float*)d_in[2];
    const float* b1  = (const float*)d_in[3];
    const float* Wl  = (const float*)d_in[4];
    const float* bl  = (const float*)d_in[5];
    const float* Wr  = (const float*)d_in[6];
    const float* br  = (const float*)d_in[7];
    const float* Wlg = (const float*)d_in[8];
    const float* blg = (const float*)d_in[9];
    const float* Wrg = (const float*)d_in[10];
    const float* brg = (const float*)d_in[11];
    const float* Wog = (const float*)d_in[12];
    const float* bog = (const float*)d_in[13];
    const float* g2  = (const float*)d_in[14];
    const float* b2  = (const float*)d_in[15];
    const float* Wo  = (const float*)d_in[16];
    const float* bo  = (const float*)d_in[17];

    float* out = (float*)d_out;
    unsigned short* ogu = (unsigned short*)d_out;   // bf16 gate @ 512B/row stride
    char* wsb = (char*)d_ws;
    unsigned short* leftT  = (unsigned short*)wsb;                    // 32 MB
    unsigned short* rightT = (unsigned short*)(wsb + 33554432);       // 32 MB
    unsigned short* tri    = (unsigned short*)(wsb + 67108864);       // 32 MB
    unsigned short* WTf    = (unsigned short*)(wsb + 100663296);      // 192 KB

    hipLaunchKernelGGL(k0_wt, dim3(48), dim3(256), 0, stream,
                       Wl, Wr, Wlg, Wrg, Wog, Wo, WTf);
    hipLaunchKernelGGL(k1_proj, dim3(Bn*Nn*8), dim3(512), 0, stream,
                       x, msk, g1, b1, WTf, bl, br, blg, brg, bog,
                       leftT, rightT, ogu);
    hipLaunchKernelGGL(k2_tri, dim3(512), dim3(512), 0, stream,
                       leftT, rightT, tri);
    hipLaunchKernelGGL(k3_out, dim3(Bn*Nn*8), dim3(256), 0, stream,
                       tri, ogu, g2, b2, WTf, bo, out);
}